// Round 2
// baseline (416.849 us; speedup 1.0000x reference)
//
#include <hip/hip_runtime.h>

typedef __bf16 bf16;
typedef __bf16 bf16x8 __attribute__((ext_vector_type(8)));
typedef float f32x4 __attribute__((ext_vector_type(4)));

#define DEV __device__ __forceinline__

// async global->LDS, 16B per lane; lds base must be wave-uniform (HW adds lane*16)
DEV void gload_lds16(const void* g, void* l) {
  __builtin_amdgcn_global_load_lds((const __attribute__((address_space(1))) void*)g,
                                   (__attribute__((address_space(3))) void*)l,
                                   16, 0, 0);
}

// ---------------- cast fp32 -> bf16, 8 elems/thread ----------------
__global__ void cast_kernel(const float* __restrict__ in, bf16* __restrict__ out, int n8) {
  int idx = blockIdx.x * blockDim.x + threadIdx.x;
  int stride = gridDim.x * blockDim.x;
  for (int i = idx; i < n8; i += stride) {
    const float4* p = (const float4*)(in + (size_t)i * 8);
    float4 a = p[0], b = p[1];
    bf16x8 v;
    v[0] = (bf16)a.x; v[1] = (bf16)a.y; v[2] = (bf16)a.z; v[3] = (bf16)a.w;
    v[4] = (bf16)b.x; v[5] = (bf16)b.y; v[6] = (bf16)b.z; v[7] = (bf16)b.w;
    *(bf16x8*)(out + (size_t)i * 8) = v;
  }
}

// ---------------- transpose + cast + scale: in[R][C] f32 -> out[C][R] bf16 ----------------
__global__ void transpose_cast(const float* __restrict__ in, bf16* __restrict__ out,
                               int R, int C, float scale) {
  __shared__ float tile[32][33];
  int c0 = blockIdx.x * 32, r0 = blockIdx.y * 32;
  int tx = threadIdx.x & 31, ty = threadIdx.x >> 5;  // 256 threads = 32x8
  for (int i = ty; i < 32; i += 8) tile[i][tx] = in[(size_t)(r0 + i) * C + c0 + tx];
  __syncthreads();
  for (int i = ty; i < 32; i += 8)
    out[(size_t)(c0 + i) * R + r0 + tx] = (bf16)(tile[tx][i] * scale);
}

// ---------------- bf16 GEMM, B given transposed (Bt[N][K]) ----------------
// m97 structure: BK=32, global_load_lds width 16, each wave owns a 64x64 subtile.
// OMODE 0: C[M][N] row-major.  OMODE 1: vT store — C[(b*64+col)*2048 + (row&2047)], b=row>>11.
template <int BM, int BN, typename OutT, int OMODE>
__global__ __launch_bounds__((BM / 64) * (BN / 64) * 64)
void gemm_bt(const bf16* __restrict__ A, const bf16* __restrict__ Bt,
             OutT* __restrict__ C, int M, int N, int K) {
  constexpr int WC = BN / 64;
  constexpr int NW = (BM / 64) * WC;
  constexpr int THREADS = NW * 64;
  __shared__ __align__(16) bf16 As[BM * 32];
  __shared__ __align__(16) bf16 Bs[BN * 32];
  const int tid = threadIdx.x;
  const int wid = tid >> 6, lane = tid & 63;
  const int wr = wid / WC, wc = wid % WC;
  const int lx = lane & 15, g = lane >> 4;
  const size_t bm = (size_t)blockIdx.x * BM;
  const size_t bn = (size_t)blockIdx.y * BN;
  f32x4 acc[4][4] = {};

  for (int k0 = 0; k0 < K; k0 += 32) {
#pragma unroll
    for (int i = 0; i < (BM * 4) / THREADS; ++i) {
      int c = i * THREADS + wid * 64 + lane;
      const bf16* gp = A + (bm + (size_t)(c >> 2)) * K + k0 + (c & 3) * 8;
      gload_lds16(gp, (char*)As + (size_t)(i * THREADS + wid * 64) * 16);
    }
#pragma unroll
    for (int i = 0; i < (BN * 4) / THREADS; ++i) {
      int c = i * THREADS + wid * 64 + lane;
      const bf16* gp = Bt + (bn + (size_t)(c >> 2)) * K + k0 + (c & 3) * 8;
      gload_lds16(gp, (char*)Bs + (size_t)(i * THREADS + wid * 64) * 16);
    }
    __syncthreads();
    bf16x8 af[4], bfr[4];
#pragma unroll
    for (int m = 0; m < 4; ++m)
      af[m] = *(const bf16x8*)&As[(wr * 64 + m * 16 + lx) * 32 + g * 8];
#pragma unroll
    for (int n = 0; n < 4; ++n)
      bfr[n] = *(const bf16x8*)&Bs[(wc * 64 + n * 16 + lx) * 32 + g * 8];
#pragma unroll
    for (int m = 0; m < 4; ++m)
#pragma unroll
      for (int n = 0; n < 4; ++n)
        acc[m][n] = __builtin_amdgcn_mfma_f32_16x16x32_bf16(af[m], bfr[n], acc[m][n], 0, 0, 0);
    __syncthreads();
  }

#pragma unroll
  for (int m = 0; m < 4; ++m) {
#pragma unroll
    for (int n = 0; n < 4; ++n) {
      size_t row = bm + wr * 64 + m * 16 + g * 4;
      size_t col = bn + wc * 64 + n * 16 + lx;
#pragma unroll
      for (int j = 0; j < 4; ++j) {
        float v = acc[m][n][j];
        if constexpr (OMODE == 0) {
          C[(row + j) * N + col] = (OutT)v;
        } else {
          size_t r = row + j;
          size_t bb = r >> 11, nn = r & 2047;
          C[(bb * 64 + col) * 2048 + nn] = (OutT)v;
        }
      }
    }
  }
}

// ---------------- causal multi-query flash attention ----------------
// grid (16 qtiles, 16 heads, 4 batch); 4 independent waves/block, 32 q-rows each.
// q pre-scaled by (1/sqrt(64))*log2(e) via Wq; exp2-based online softmax.
__global__ __launch_bounds__(256)
void attn_kernel(const bf16* __restrict__ q, const bf16* __restrict__ k,
                 const bf16* __restrict__ vT, bf16* __restrict__ o) {
  const int qt = blockIdx.x, h = blockIdx.y, b = blockIdx.z;
  const int wid = threadIdx.x >> 6, lane = threadIdx.x & 63;
  const int lx = lane & 15, g = lane >> 4;
  const int qw0 = qt * 128 + wid * 32;
  __shared__ __align__(16) bf16 Plds[4][32][40];  // per-wave P, 80B row stride (16B aligned)
  const bf16* kb = k + (size_t)b * 2048 * 64;
  const bf16* vb = vT + (size_t)b * 64 * 2048;

  bf16x8 qf[2][2];
#pragma unroll
  for (int m = 0; m < 2; ++m)
#pragma unroll
    for (int kk = 0; kk < 2; ++kk)
      qf[m][kk] = *(const bf16x8*)&q[(size_t)(b * 2048 + qw0 + m * 16 + lx) * 1024 +
                                     h * 64 + kk * 32 + g * 8];

  float mrun[2][4], lpart[2][4];
  f32x4 oacc[2][4] = {};
#pragma unroll
  for (int m = 0; m < 2; ++m)
#pragma unroll
    for (int j = 0; j < 4; ++j) { mrun[m][j] = -__builtin_inff(); lpart[m][j] = 0.f; }

  const int nkt = qw0 / 32 + 1;
  for (int t = 0; t < nkt; ++t) {
    const int kt0 = t * 32;
    bf16x8 kf[2][2], vf[4];
#pragma unroll
    for (int kt = 0; kt < 2; ++kt)
#pragma unroll
      for (int kk = 0; kk < 2; ++kk)
        kf[kt][kk] = *(const bf16x8*)&kb[(size_t)(kt0 + kt * 16 + lx) * 64 + kk * 32 + g * 8];
#pragma unroll
    for (int d = 0; d < 4; ++d)
      vf[d] = *(const bf16x8*)&vb[(size_t)(d * 16 + lx) * 2048 + kt0 + g * 8];

#pragma unroll
    for (int m = 0; m < 2; ++m) {
      f32x4 z = {0.f, 0.f, 0.f, 0.f};
      f32x4 s0 = __builtin_amdgcn_mfma_f32_16x16x32_bf16(qf[m][0], kf[0][0], z, 0, 0, 0);
      s0 = __builtin_amdgcn_mfma_f32_16x16x32_bf16(qf[m][1], kf[0][1], s0, 0, 0, 0);
      f32x4 s1 = __builtin_amdgcn_mfma_f32_16x16x32_bf16(qf[m][0], kf[1][0], z, 0, 0, 0);
      s1 = __builtin_amdgcn_mfma_f32_16x16x32_bf16(qf[m][1], kf[1][1], s1, 0, 0, 0);
      const int rbase = qw0 + m * 16 + g * 4;
      if (kt0 + 31 > qw0 + m * 16) {  // diagonal tile: apply causal mask
#pragma unroll
        for (int j = 0; j < 4; ++j) {
          if (kt0 + lx > rbase + j) s0[j] = -__builtin_inff();
          if (kt0 + 16 + lx > rbase + j) s1[j] = -__builtin_inff();
        }
      }
#pragma unroll
      for (int j = 0; j < 4; ++j) {
        float tm = fmaxf(s0[j], s1[j]);
        tm = fmaxf(tm, __shfl_xor(tm, 1));
        tm = fmaxf(tm, __shfl_xor(tm, 2));
        tm = fmaxf(tm, __shfl_xor(tm, 4));
        tm = fmaxf(tm, __shfl_xor(tm, 8));
        float nm = fmaxf(mrun[m][j], tm);
        float fac = exp2f(mrun[m][j] - nm);
        mrun[m][j] = nm;
        float p0 = exp2f(s0[j] - nm);
        float p1 = exp2f(s1[j] - nm);
        lpart[m][j] = lpart[m][j] * fac + p0 + p1;
#pragma unroll
        for (int d = 0; d < 4; ++d) oacc[m][d][j] *= fac;
        Plds[wid][m * 16 + g * 4 + j][lx] = (bf16)p0;
        Plds[wid][m * 16 + g * 4 + j][16 + lx] = (bf16)p1;
      }
    }
    __threadfence_block();  // order P writes (cross-lane) before P reads, same wave
#pragma unroll
    for (int m = 0; m < 2; ++m) {
      bf16x8 pa = *(const bf16x8*)&Plds[wid][m * 16 + lx][g * 8];
#pragma unroll
      for (int d = 0; d < 4; ++d)
        oacc[m][d] = __builtin_amdgcn_mfma_f32_16x16x32_bf16(pa, vf[d], oacc[m][d], 0, 0, 0);
    }
  }

#pragma unroll
  for (int m = 0; m < 2; ++m) {
    float inv[4];
#pragma unroll
    for (int j = 0; j < 4; ++j) {
      float s = lpart[m][j];
      s += __shfl_xor(s, 1);
      s += __shfl_xor(s, 2);
      s += __shfl_xor(s, 4);
      s += __shfl_xor(s, 8);
      inv[j] = 1.0f / s;
    }
#pragma unroll
    for (int d = 0; d < 4; ++d) {
      size_t row = (size_t)(b * 2048 + qw0 + m * 16 + g * 4);
      size_t col = (size_t)(h * 64 + d * 16 + lx);
#pragma unroll
      for (int j = 0; j < 4; ++j)
        o[(row + j) * 1024 + col] = (bf16)(oacc[m][d][j] * inv[j]);
    }
  }
}

// ---------------- launch ----------------
extern "C" void kernel_launch(void* const* d_in, const int* in_sizes, int n_in,
                              void* d_out, int out_size, void* d_ws, size_t ws_size,
                              hipStream_t stream) {
  const float* Q  = (const float*)d_in[0];
  const float* K  = (const float*)d_in[1];
  const float* V  = (const float*)d_in[2];
  const float* wq = (const float*)d_in[3];
  const float* wk = (const float*)d_in[4];
  const float* wv = (const float*)d_in[5];
  const float* wo = (const float*)d_in[6];
  float* out = (float*)d_out;

  char* ws = (char*)d_ws;
  bf16* Qb  = (bf16*)(ws);                          // 8192x1024  (16 MB)
  bf16* Kb  = (bf16*)(ws + (16ull << 20));          // 16 MB
  bf16* Vb  = (bf16*)(ws + (32ull << 20));          // 16 MB
  bf16* qp  = (bf16*)(ws + (48ull << 20));          // q proj bf16, 16 MB
  bf16* ab  = (bf16*)(ws + (64ull << 20));          // attn out bf16, 16 MB
  bf16* kp  = (bf16*)(ws + (80ull << 20));          // 8192x64, 1 MB
  bf16* vTp = (bf16*)(ws + (81ull << 20));          // [4][64][2048], 1 MB
  bf16* wqT = (bf16*)(ws + (82ull << 20));          // 2 MB
  bf16* woT = (bf16*)(ws + (84ull << 20));          // 2 MB
  bf16* wkT = (bf16*)(ws + (86ull << 20));          // 128 KB
  bf16* wvT = (bf16*)(ws + (86ull << 20) + (1ull << 18));

  const int N8 = 8192 * 1024 / 8;
  cast_kernel<<<2048, 256, 0, stream>>>(Q, Qb, N8);
  cast_kernel<<<2048, 256, 0, stream>>>(K, Kb, N8);
  cast_kernel<<<2048, 256, 0, stream>>>(V, Vb, N8);

  // fold softmax scale (1/sqrt(64)) and log2(e) into Wq
  const float SCALE = 0.125f * 1.44269504088896340736f;
  transpose_cast<<<dim3(32, 32), 256, 0, stream>>>(wq, wqT, 1024, 1024, SCALE);
  transpose_cast<<<dim3(2, 32), 256, 0, stream>>>(wk, wkT, 1024, 64, 1.0f);
  transpose_cast<<<dim3(2, 32), 256, 0, stream>>>(wv, wvT, 1024, 64, 1.0f);
  transpose_cast<<<dim3(32, 32), 256, 0, stream>>>(wo, woT, 1024, 1024, 1.0f);

  gemm_bt<128, 128, bf16, 0><<<dim3(64, 8), 256, 0, stream>>>(Qb, wqT, qp, 8192, 1024, 1024);
  gemm_bt<128, 64, bf16, 0><<<dim3(64, 1), 128, 0, stream>>>(Kb, wkT, kp, 8192, 64, 1024);
  gemm_bt<128, 64, bf16, 1><<<dim3(64, 1), 128, 0, stream>>>(Vb, wvT, vTp, 8192, 64, 1024);

  attn_kernel<<<dim3(16, 16, 4), 256, 0, stream>>>(qp, kp, vTp, ab);

  gemm_bt<128, 128, float, 0><<<dim3(64, 8), 256, 0, stream>>>(ab, woT, out, 8192, 1024, 1024);
}

// Round 3
// 263.196 us; speedup vs baseline: 1.5838x; 1.5838x over previous
//
#include <hip/hip_runtime.h>

typedef __bf16 bf16;
typedef unsigned int u32;
typedef __bf16 bf16x8 __attribute__((ext_vector_type(8)));
typedef float f32x4 __attribute__((ext_vector_type(4)));
typedef float f32x16 __attribute__((ext_vector_type(16)));

#define DEV __device__ __forceinline__

// async global->LDS, 16B per lane; lds base must be wave-uniform (HW adds lane*16)
DEV void gload_lds16(const void* g, void* l) {
  __builtin_amdgcn_global_load_lds((const __attribute__((address_space(1))) void*)g,
                                   (__attribute__((address_space(3))) void*)l,
                                   16, 0, 0);
}

DEV u32 pack2(float a, float b) {
  unsigned short ua = __builtin_bit_cast(unsigned short, (bf16)a);
  unsigned short ub = __builtin_bit_cast(unsigned short, (bf16)b);
  return (u32)ua | ((u32)ub << 16);
}

// ---------------- cast fp32 -> bf16, 8 elems/thread ----------------
__global__ void cast_kernel(const float* __restrict__ in, bf16* __restrict__ out, int n8) {
  int idx = blockIdx.x * blockDim.x + threadIdx.x;
  int stride = gridDim.x * blockDim.x;
  for (int i = idx; i < n8; i += stride) {
    const float4* p = (const float4*)(in + (size_t)i * 8);
    float4 a = p[0], b = p[1];
    bf16x8 v;
    v[0] = (bf16)a.x; v[1] = (bf16)a.y; v[2] = (bf16)a.z; v[3] = (bf16)a.w;
    v[4] = (bf16)b.x; v[5] = (bf16)b.y; v[6] = (bf16)b.z; v[7] = (bf16)b.w;
    *(bf16x8*)(out + (size_t)i * 8) = v;
  }
}

// ---------------- transpose + cast + scale: in[R][C] f32 -> out[C][R] bf16 ----------------
__global__ void transpose_cast(const float* __restrict__ in, bf16* __restrict__ out,
                               int R, int C, float scale) {
  __shared__ float tile[32][33];
  int c0 = blockIdx.x * 32, r0 = blockIdx.y * 32;
  int tx = threadIdx.x & 31, ty = threadIdx.x >> 5;  // 256 threads = 32x8
  for (int i = ty; i < 32; i += 8) tile[i][tx] = in[(size_t)(r0 + i) * C + c0 + tx];
  __syncthreads();
  for (int i = ty; i < 32; i += 8)
    out[(size_t)(c0 + i) * R + r0 + tx] = (bf16)(tile[tx][i] * scale);
}

// ---------------- bf16 GEMM, B given transposed (Bt[N][K]) ----------------
// m97 structure: BK=32, global_load_lds width 16, each wave owns a 64x64 subtile.
// OMODE 0: C[M][N] row-major.  OMODE 1: vT store — C[(b*64+col)*2048 + (row&2047)], b=row>>11.
template <int BM, int BN, typename OutT, int OMODE>
__global__ __launch_bounds__((BM / 64) * (BN / 64) * 64)
void gemm_bt(const bf16* __restrict__ A, const bf16* __restrict__ Bt,
             OutT* __restrict__ C, int M, int N, int K) {
  constexpr int WC = BN / 64;
  constexpr int NW = (BM / 64) * WC;
  constexpr int THREADS = NW * 64;
  __shared__ __align__(16) bf16 As[BM * 32];
  __shared__ __align__(16) bf16 Bs[BN * 32];
  const int tid = threadIdx.x;
  const int wid = tid >> 6, lane = tid & 63;
  const int wr = wid / WC, wc = wid % WC;
  const int lx = lane & 15, g = lane >> 4;
  const size_t bm = (size_t)blockIdx.x * BM;
  const size_t bn = (size_t)blockIdx.y * BN;
  f32x4 acc[4][4] = {};

  for (int k0 = 0; k0 < K; k0 += 32) {
#pragma unroll
    for (int i = 0; i < (BM * 4) / THREADS; ++i) {
      int c = i * THREADS + wid * 64 + lane;
      const bf16* gp = A + (bm + (size_t)(c >> 2)) * K + k0 + (c & 3) * 8;
      gload_lds16(gp, (char*)As + (size_t)(i * THREADS + wid * 64) * 16);
    }
#pragma unroll
    for (int i = 0; i < (BN * 4) / THREADS; ++i) {
      int c = i * THREADS + wid * 64 + lane;
      const bf16* gp = Bt + (bn + (size_t)(c >> 2)) * K + k0 + (c & 3) * 8;
      gload_lds16(gp, (char*)Bs + (size_t)(i * THREADS + wid * 64) * 16);
    }
    __syncthreads();
    bf16x8 af[4], bfr[4];
#pragma unroll
    for (int m = 0; m < 4; ++m)
      af[m] = *(const bf16x8*)&As[(wr * 64 + m * 16 + lx) * 32 + g * 8];
#pragma unroll
    for (int n = 0; n < 4; ++n)
      bfr[n] = *(const bf16x8*)&Bs[(wc * 64 + n * 16 + lx) * 32 + g * 8];
#pragma unroll
    for (int m = 0; m < 4; ++m)
#pragma unroll
      for (int n = 0; n < 4; ++n)
        acc[m][n] = __builtin_amdgcn_mfma_f32_16x16x32_bf16(af[m], bfr[n], acc[m][n], 0, 0, 0);
    __syncthreads();
  }

#pragma unroll
  for (int m = 0; m < 4; ++m) {
#pragma unroll
    for (int n = 0; n < 4; ++n) {
      size_t row = bm + wr * 64 + m * 16 + g * 4;
      size_t col = bn + wc * 64 + n * 16 + lx;
#pragma unroll
      for (int j = 0; j < 4; ++j) {
        float v = acc[m][n][j];
        if constexpr (OMODE == 0) {
          C[(row + j) * N + col] = (OutT)v;
        } else {
          size_t r = row + j;
          size_t bb = r >> 11, nn = r & 2047;
          C[(bb * 64 + col) * 2048 + nn] = (OutT)v;
        }
      }
    }
  }
}

// ---------------- causal multi-query flash attention (swapped QK^T, 32x32 MFMA) ----
// grid (16, 16 heads, 4 batch), 128 threads = 2 waves. Wave w of block bx owns
// strips {p, 63-p} where p = bx*2+w  -> exactly 65 KV-tiles per wave (balanced).
// Each strip = 32 q-rows. S^T = mfma(K, Q): lane holds 16 scores of query (lane&31),
// key = kt0 + (r&3)+8*(r>>2)+4*(lane>>5). Softmax in-register; P rebuilt to the PV
// A-fragment via bf16 pack + shfl_xor(32); defer-max skips O-rescale when possible.
__global__ __launch_bounds__(128)
void attn_kernel(const bf16* __restrict__ q, const bf16* __restrict__ k,
                 const bf16* __restrict__ vT, bf16* __restrict__ o) {
  const int h = blockIdx.y, b = blockIdx.z;
  const int wid = threadIdx.x >> 6, lane = threadIdx.x & 63;
  const int lq = lane & 31, hi = lane >> 5;
  const int pairIdx = blockIdx.x * 2 + wid;  // 0..31
  __shared__ float bc[2][32];

  const bf16* kb = k + (size_t)b * 2048 * 64;
  const bf16* vb = vT + (size_t)b * 64 * 2048;

#pragma unroll
  for (int rep = 0; rep < 2; ++rep) {
    const int strip = rep ? 63 - pairIdx : pairIdx;
    const int qb = strip * 32;

    bf16x8 qf[4];
    const bf16* qrow = q + (size_t)(b * 2048 + qb + lq) * 1024 + h * 64 + hi * 8;
#pragma unroll
    for (int i = 0; i < 4; ++i) qf[i] = *(const bf16x8*)(qrow + i * 16);

    f32x16 O0 = {}, O1 = {};
    float m = -__builtin_inff(), l = 0.f;
    const int nt = strip + 1;

    for (int t = 0; t < nt; ++t) {
      const int kt0 = t * 32;
      // K as A-operand: row = key = kt0+lq, k-dim slice i covers dk [16i,16i+16)
      bf16x8 kf[4];
      const bf16* krow = kb + (size_t)(kt0 + lq) * 64 + hi * 8;
#pragma unroll
      for (int i = 0; i < 4; ++i) kf[i] = *(const bf16x8*)(krow + i * 16);
      // V as B-operand from vT[d][key]: col = d = dblk*32+lq, rows = key slice
      bf16x8 vf[2][2];
#pragma unroll
      for (int d = 0; d < 2; ++d)
#pragma unroll
        for (int ks = 0; ks < 2; ++ks)
          vf[d][ks] = *(const bf16x8*)(vb + (size_t)(d * 32 + lq) * 2048 +
                                       kt0 + ks * 16 + hi * 8);

      // S^T[key][q]: 4 MFMAs over dk=64
      f32x16 S = {};
#pragma unroll
      for (int i = 0; i < 4; ++i)
        S = __builtin_amdgcn_mfma_f32_32x32x16_bf16(kf[i], qf[i], S, 0, 0, 0);

      if (t == nt - 1) {  // diagonal tile: kt0 == qb, mask key_local > q_local
#pragma unroll
        for (int r = 0; r < 16; ++r) {
          int kr = (r & 3) + 8 * (r >> 2) + 4 * hi;
          if (kr > lq) S[r] = -__builtin_inff();
        }
      }

      // row max (query row lives in lanes lq and lq+32, disjoint key halves)
      float pm = S[0];
#pragma unroll
      for (int r = 1; r < 16; ++r) pm = fmaxf(pm, S[r]);
      pm = fmaxf(pm, __shfl_xor(pm, 32));

      if (!__all(pm <= m + 8.0f)) {  // rescale path (rare after warmup)
        float mn = fmaxf(m, pm);
        float fac = __builtin_amdgcn_exp2f(m - mn);
        m = mn;
        l *= fac;
        if (hi == 0) bc[wid][lq] = fac;
        __threadfence_block();
#pragma unroll
        for (int r = 0; r < 16; ++r) {
          float fr = bc[wid][(r & 3) + 8 * (r >> 2) + 4 * hi];
          O0[r] *= fr;
          O1[r] *= fr;
        }
      }

      float p[16];
      float ls = 0.f;
#pragma unroll
      for (int r = 0; r < 16; ++r) {
        p[r] = __builtin_amdgcn_exp2f(S[r] - m);
        ls += p[r];
      }
      ls += __shfl_xor(ls, 32);
      l += ls;

      // rebuild PV A-fragments: pack to bf16 pairs, exchange across lane-32 halves
      u32 w[8];
#pragma unroll
      for (int i = 0; i < 8; ++i) w[i] = pack2(p[2 * i], p[2 * i + 1]);
      u32 sw0 = (u32)__shfl_xor((int)w[0], 32), sw1 = (u32)__shfl_xor((int)w[1], 32);
      u32 sw2 = (u32)__shfl_xor((int)w[2], 32), sw3 = (u32)__shfl_xor((int)w[3], 32);
      u32 sw4 = (u32)__shfl_xor((int)w[4], 32), sw5 = (u32)__shfl_xor((int)w[5], 32);
      u32 sw6 = (u32)__shfl_xor((int)w[6], 32), sw7 = (u32)__shfl_xor((int)w[7], 32);
      union { u32 d[4]; bf16x8 v; } f0, f1;
      f0.d[0] = hi ? sw2 : w[0];
      f0.d[1] = hi ? sw3 : w[1];
      f0.d[2] = hi ? w[2] : sw0;
      f0.d[3] = hi ? w[3] : sw1;
      f1.d[0] = hi ? sw6 : w[4];
      f1.d[1] = hi ? sw7 : w[5];
      f1.d[2] = hi ? w[6] : sw4;
      f1.d[3] = hi ? w[7] : sw5;

      O0 = __builtin_amdgcn_mfma_f32_32x32x16_bf16(f0.v, vf[0][0], O0, 0, 0, 0);
      O0 = __builtin_amdgcn_mfma_f32_32x32x16_bf16(f1.v, vf[0][1], O0, 0, 0, 0);
      O1 = __builtin_amdgcn_mfma_f32_32x32x16_bf16(f0.v, vf[1][0], O1, 0, 0, 0);
      O1 = __builtin_amdgcn_mfma_f32_32x32x16_bf16(f1.v, vf[1][1], O1, 0, 0, 0);
    }

    // epilogue: normalize by 1/l (broadcast per output row) and store
    float linv = 1.0f / l;
    if (hi == 0) bc[wid][lq] = linv;
    __threadfence_block();
#pragma unroll
    for (int r = 0; r < 16; ++r) {
      int row = (r & 3) + 8 * (r >> 2) + 4 * hi;
      float sc = bc[wid][row];
      size_t base = (size_t)(b * 2048 + qb + row) * 1024 + h * 64;
      o[base + lq] = (bf16)(O0[r] * sc);
      o[base + 32 + lq] = (bf16)(O1[r] * sc);
    }
  }
}

// ---------------- launch ----------------
extern "C" void kernel_launch(void* const* d_in, const int* in_sizes, int n_in,
                              void* d_out, int out_size, void* d_ws, size_t ws_size,
                              hipStream_t stream) {
  const float* Q  = (const float*)d_in[0];
  const float* K  = (const float*)d_in[1];
  const float* V  = (const float*)d_in[2];
  const float* wq = (const float*)d_in[3];
  const float* wk = (const float*)d_in[4];
  const float* wv = (const float*)d_in[5];
  const float* wo = (const float*)d_in[6];
  float* out = (float*)d_out;

  char* ws = (char*)d_ws;
  bf16* Qb  = (bf16*)(ws);                          // 8192x1024  (16 MB)
  bf16* Kb  = (bf16*)(ws + (16ull << 20));          // 16 MB
  bf16* Vb  = (bf16*)(ws + (32ull << 20));          // 16 MB
  bf16* qp  = (bf16*)(ws + (48ull << 20));          // q proj bf16, 16 MB
  bf16* ab  = (bf16*)(ws + (64ull << 20));          // attn out bf16, 16 MB
  bf16* kp  = (bf16*)(ws + (80ull << 20));          // 8192x64, 1 MB
  bf16* vTp = (bf16*)(ws + (81ull << 20));          // [4][64][2048], 1 MB
  bf16* wqT = (bf16*)(ws + (82ull << 20));          // 2 MB
  bf16* woT = (bf16*)(ws + (84ull << 20));          // 2 MB
  bf16* wkT = (bf16*)(ws + (86ull << 20));          // 128 KB
  bf16* wvT = (bf16*)(ws + (86ull << 20) + (1ull << 18));

  const int N8 = 8192 * 1024 / 8;
  cast_kernel<<<2048, 256, 0, stream>>>(Q, Qb, N8);
  cast_kernel<<<2048, 256, 0, stream>>>(K, Kb, N8);
  cast_kernel<<<2048, 256, 0, stream>>>(V, Vb, N8);

  // fold softmax scale (1/sqrt(64)) and log2(e) into Wq (exp2-based softmax)
  const float SCALE = 0.125f * 1.44269504088896340736f;
  transpose_cast<<<dim3(32, 32), 256, 0, stream>>>(wq, wqT, 1024, 1024, SCALE);
  transpose_cast<<<dim3(2, 32), 256, 0, stream>>>(wk, wkT, 1024, 64, 1.0f);
  transpose_cast<<<dim3(2, 32), 256, 0, stream>>>(wv, wvT, 1024, 64, 1.0f);
  transpose_cast<<<dim3(32, 32), 256, 0, stream>>>(wo, woT, 1024, 1024, 1.0f);

  gemm_bt<128, 128, bf16, 0><<<dim3(64, 8), 256, 0, stream>>>(Qb, wqT, qp, 8192, 1024, 1024);
  gemm_bt<128, 64, bf16, 0><<<dim3(64, 1), 128, 0, stream>>>(Kb, wkT, kp, 8192, 64, 1024);
  gemm_bt<128, 64, bf16, 1><<<dim3(64, 1), 128, 0, stream>>>(Vb, wvT, vTp, 8192, 64, 1024);

  attn_kernel<<<dim3(16, 16, 4), 128, 0, stream>>>(qp, kp, vTp, ab);

  gemm_bt<128, 128, float, 0><<<dim3(64, 8), 256, 0, stream>>>(ab, woT, out, 8192, 1024, 1024);
}